// Round 3
// baseline (232.732 us; speedup 1.0000x reference)
//
#include <hip/hip_runtime.h>
#include <hip/hip_fp16.h>

#define ND 100000   // N_NODES
#define NE 50000    // N_EDGES
#define AR 32       // EDGE_ARITY
#define DG 16       // NODE_DEG
#define D  128      // D_IN == D_OUT == TV

typedef _Float16 half8_t __attribute__((ext_vector_type(8)));
typedef _Float16 half4_t __attribute__((ext_vector_type(4)));
typedef float    f32x4_t __attribute__((ext_vector_type(4)));

// A-row stride in LDS (halves): 128 + 8 pad -> keeps 16 B alignment for half8
// loads; 2-way bank aliasing on A-frag reads is free.
#define APAD 136

// ---------------------------------------------------------------------------
// K0: fused prep.
//   blocks 0..63 : convert w1,w2 (f32 row-major [k][n]) -> fragment-major fp16.
//     o = ((ntile*4 + ktile)*64 + lane)*8 + j
//     <-> B[k = ktile*32 + (lane>>4)*8 + j][n = ntile*16 + (lane&15)]
//   block 64     : inter_nw = mean(cos(w3 rows, w3[0])) -> scalar in ws.
// ---------------------------------------------------------------------------
__global__ __launch_bounds__(256) void k_prep(const float* __restrict__ w1,
                                              const float* __restrict__ w2,
                                              const float* __restrict__ w3,
                                              _Float16* __restrict__ w1f,
                                              _Float16* __restrict__ w2f,
                                              float* __restrict__ inter_out) {
    if (blockIdx.x == 64) {
        __shared__ float red[128];
        int j = threadIdx.x;
        if (j < 128) {
            float dot = 0.f, sq = 0.f, sq0 = 0.f;
            #pragma unroll 8
            for (int k = 0; k < D; ++k) {
                float wj = w3[j * D + k];
                float w0 = w3[k];
                dot += wj * w0;
                sq  += wj * wj;
                sq0 += w0 * w0;
            }
            red[j] = dot / (sqrtf(sq0) * sqrtf(sq));
        }
        __syncthreads();
        if (j == 0) {
            float s = 0.f;
            for (int i = 0; i < 128; ++i) s += red[i];
            inter_out[0] = s / 128.f;
        }
        return;
    }
    int o = blockIdx.x * 256 + threadIdx.x;   // 0..16383
    int j    = o & 7;
    int lane = (o >> 3) & 63;
    int frag = o >> 9;                        // 0..31
    int ntile = frag >> 2, ktile = frag & 3;
    int n = ntile * 16 + (lane & 15);
    int k = ktile * 32 + (lane >> 4) * 8 + j;
    w1f[o] = (_Float16)w1[k * D + n];
    w2f[o] = (_Float16)w2[k * D + n];
}

// ---------------------------------------------------------------------------
// K1: xw = (x @ w1) * inter_nw via MFMA fp16 -> fp16 table in d_out scratch.
// 64 rows/block, 256 threads = 4 waves; wave w computes rows [w*16, w*16+16).
// ---------------------------------------------------------------------------
__global__ __launch_bounds__(256) void k_xw(const float* __restrict__ x,
                                            const _Float16* __restrict__ w1f_g,
                                            const float* __restrict__ inter_p,
                                            _Float16* __restrict__ xwh) {
    __shared__ _Float16 wfrag[D * D];     // 32 KB, fragment-major
    __shared__ _Float16 xs[64 * APAD];    // 17 KB, row-major A tile (fp16)
    int t = threadIdx.x;

    {
        const float4* src = (const float4*)w1f_g;
        float4* dst = (float4*)wfrag;
        #pragma unroll
        for (int i = 0; i < 8; ++i) dst[i * 256 + t] = src[i * 256 + t];
    }
    int rowbase = blockIdx.x * 64;
    #pragma unroll
    for (int p = 0; p < 8; ++p) {
        int idx = p * 1024 + t * 4;          // float index within tile
        int r = idx >> 7, c = idx & 127;
        int grow = rowbase + r;
        float4 v = make_float4(0.f, 0.f, 0.f, 0.f);
        if (grow < ND) v = ((const float4*)x)[(size_t)grow * 32 + (c >> 2)];
        half4_t h = { (_Float16)v.x, (_Float16)v.y, (_Float16)v.z, (_Float16)v.w };
        *(half4_t*)&xs[r * APAD + c] = h;
    }
    __syncthreads();

    int wave = t >> 6, lane = t & 63;
    int quad = lane >> 4, l15 = lane & 15;
    int m0 = wave * 16;
    float inter = inter_p[0];

    half8_t a[4];
    #pragma unroll
    for (int kt = 0; kt < 4; ++kt)
        a[kt] = *(const half8_t*)&xs[(m0 + l15) * APAD + kt * 32 + quad * 8];

    #pragma unroll
    for (int nt = 0; nt < 8; ++nt) {
        f32x4_t acc = {0.f, 0.f, 0.f, 0.f};
        #pragma unroll
        for (int kt = 0; kt < 4; ++kt) {
            half8_t b = *(const half8_t*)&wfrag[((nt * 4 + kt) * 64 + lane) * 8];
            acc = __builtin_amdgcn_mfma_f32_16x16x32_f16(a[kt], b, acc, 0, 0, 0);
        }
        int col = nt * 16 + l15;
        #pragma unroll
        for (int i = 0; i < 4; ++i) {
            int grow = rowbase + m0 + quad * 4 + i;
            if (grow < ND)
                xwh[(size_t)grow * D + col] = (_Float16)(acc[i] * inter);
        }
    }
}

// ---------------------------------------------------------------------------
// K2a: edge gather. One wave per edge, NO LDS, no barrier -> max occupancy.
// Each lane loads half8 (16 B); 4 lane-groups of 16 cover 4 arity rows per
// iteration -> 8 independent 1 KB wave-loads in flight.
// ea[e] = relu(sum_a w_a * xw[seq[e,a]]) stored fp16.
// ---------------------------------------------------------------------------
__global__ __launch_bounds__(256) void k_gather_e(const int* __restrict__ seq,
                                                  const _Float16* __restrict__ xwh,
                                                  _Float16* __restrict__ ea) {
    int t = threadIdx.x;
    int wave = t >> 6, lane = t & 63;
    int e = blockIdx.x * 4 + wave;           // 12500*4 == 50000 exact
    int grp = lane >> 4, il = lane & 15;

    int sval = seq[(size_t)e * AR + (lane & 31)];
    unsigned long long b = __ballot(sval > 0);
    int cnt = __popcll((unsigned long long)(b & 0xffffffffULL));
    const float wuni = 1.f / 32.f;
    float wv = (cnt > 0) ? 1.f / (float)cnt : wuni;

    float acc[8] = {};
    #pragma unroll
    for (int i = 0; i < 8; ++i) {
        int aslot = i * 4 + grp;
        int srow = __shfl(sval, aslot, 64);
        float wa = (cnt > 0) ? ((srow > 0) ? wv : 0.f) : wuni;
        half8_t v = *(const half8_t*)(xwh + (size_t)srow * D + il * 8);
        #pragma unroll
        for (int jj = 0; jj < 8; ++jj) acc[jj] = fmaf(wa, (float)v[jj], acc[jj]);
    }
    #pragma unroll
    for (int jj = 0; jj < 8; ++jj) {
        acc[jj] += __shfl_down(acc[jj], 32, 64);
        acc[jj] += __shfl_down(acc[jj], 16, 64);
    }
    if (lane < 16) {
        half8_t h;
        #pragma unroll
        for (int jj = 0; jj < 8; ++jj) h[jj] = (_Float16)fmaxf(acc[jj], 0.f);
        *(half8_t*)(ea + (size_t)e * D + il * 8) = h;
    }
}

// ---------------------------------------------------------------------------
// K2b: e1 = ea @ w2 via MFMA (pure GEMM, ea already relu'd).
// 64 rows/block, identical structure to k_xw but fp16 A input, no scale.
// ---------------------------------------------------------------------------
__global__ __launch_bounds__(256) void k_gemm_e(const _Float16* __restrict__ ea,
                                                const _Float16* __restrict__ w2f_g,
                                                _Float16* __restrict__ e1h) {
    __shared__ _Float16 wfrag[D * D];     // 32 KB
    __shared__ _Float16 et[64 * APAD];    // 17 KB
    int t = threadIdx.x;
    {
        const float4* src = (const float4*)w2f_g;
        float4* dst = (float4*)wfrag;
        #pragma unroll
        for (int i = 0; i < 8; ++i) dst[i * 256 + t] = src[i * 256 + t];
    }
    int rowbase = blockIdx.x * 64;
    #pragma unroll
    for (int p = 0; p < 4; ++p) {
        int hidx = p * 2048 + t * 8;
        int r = hidx >> 7, c = hidx & 127;
        int grow = rowbase + r;
        int gs = (grow < NE) ? grow : (NE - 1);
        half8_t v = *(const half8_t*)(ea + (size_t)gs * D + c);
        *(half8_t*)&et[r * APAD + c] = v;
    }
    __syncthreads();

    int wave = t >> 6, lane = t & 63;
    int quad = lane >> 4, l15 = lane & 15;
    int m0 = wave * 16;

    half8_t a[4];
    #pragma unroll
    for (int kt = 0; kt < 4; ++kt)
        a[kt] = *(const half8_t*)&et[(m0 + l15) * APAD + kt * 32 + quad * 8];

    #pragma unroll
    for (int nt = 0; nt < 8; ++nt) {
        f32x4_t acc = {0.f, 0.f, 0.f, 0.f};
        #pragma unroll
        for (int kt = 0; kt < 4; ++kt) {
            half8_t b = *(const half8_t*)&wfrag[((nt * 4 + kt) * 64 + lane) * 8];
            acc = __builtin_amdgcn_mfma_f32_16x16x32_f16(a[kt], b, acc, 0, 0, 0);
        }
        int col = nt * 16 + l15;
        #pragma unroll
        for (int i = 0; i < 4; ++i) {
            int grow = rowbase + m0 + quad * 4 + i;
            if (grow < NE)
                e1h[(size_t)grow * D + col] = (_Float16)acc[i];
        }
    }
}

// ---------------------------------------------------------------------------
// K3: node gather. One wave per 2 nodes (8 loads in flight), NO LDS.
// node[n] = sum_k u_w * e1[useq[n,k]] -> f32 out.
// ---------------------------------------------------------------------------
__global__ __launch_bounds__(256) void k_gather_n(const int* __restrict__ useq,
                                                  const _Float16* __restrict__ e1h,
                                                  float* __restrict__ out) {
    int t = threadIdx.x;
    int wave = t >> 6, lane = t & 63;
    int n0 = blockIdx.x * 8 + wave * 2;      // 12500*8 == 100000 exact
    int n1 = n0 + 1;
    int grp = lane >> 4, il = lane & 15;

    // lanes 0..15 -> n0 slots, 16..31 -> n1 slots (32..63 duplicate, unused)
    int nd = grp & 1;
    int sval = useq[(size_t)(n0 + nd) * DG + il];
    unsigned long long b = __ballot(sval > 0);
    int cnt0 = __popcll((unsigned long long)(b & 0xFFFFULL));
    int cnt1 = __popcll((unsigned long long)((b >> 16) & 0xFFFFULL));
    const float wuni = 1.f / 16.f;
    float wv0 = (cnt0 > 0) ? 1.f / (float)cnt0 : wuni;
    float wv1 = (cnt1 > 0) ? 1.f / (float)cnt1 : wuni;

    float acc0[8] = {}, acc1[8] = {};
    #pragma unroll
    for (int i = 0; i < 4; ++i) {
        int slot = i * 4 + grp;
        int s0 = __shfl(sval, slot, 64);
        int s1 = __shfl(sval, 16 + slot, 64);
        float w0 = (cnt0 > 0) ? ((s0 > 0) ? wv0 : 0.f) : wuni;
        float w1 = (cnt1 > 0) ? ((s1 > 0) ? wv1 : 0.f) : wuni;
        half8_t v0 = *(const half8_t*)(e1h + (size_t)s0 * D + il * 8);
        half8_t v1 = *(const half8_t*)(e1h + (size_t)s1 * D + il * 8);
        #pragma unroll
        for (int jj = 0; jj < 8; ++jj) {
            acc0[jj] = fmaf(w0, (float)v0[jj], acc0[jj]);
            acc1[jj] = fmaf(w1, (float)v1[jj], acc1[jj]);
        }
    }
    #pragma unroll
    for (int jj = 0; jj < 8; ++jj) {
        acc0[jj] += __shfl_down(acc0[jj], 32, 64);
        acc0[jj] += __shfl_down(acc0[jj], 16, 64);
        acc1[jj] += __shfl_down(acc1[jj], 32, 64);
        acc1[jj] += __shfl_down(acc1[jj], 16, 64);
    }
    if (lane < 16) {
        float4 o0a = make_float4(acc0[0], acc0[1], acc0[2], acc0[3]);
        float4 o0b = make_float4(acc0[4], acc0[5], acc0[6], acc0[7]);
        float4 o1a = make_float4(acc1[0], acc1[1], acc1[2], acc1[3]);
        float4 o1b = make_float4(acc1[4], acc1[5], acc1[6], acc1[7]);
        float4* p0 = (float4*)(out + (size_t)n0 * D + il * 8);
        float4* p1 = (float4*)(out + (size_t)n1 * D + il * 8);
        p0[0] = o0a; p0[1] = o0b;
        p1[0] = o1a; p1[1] = o1b;
    }
}

// ---------------------------------------------------------------------------
extern "C" void kernel_launch(void* const* d_in, const int* in_sizes, int n_in,
                              void* d_out, int out_size, void* d_ws, size_t ws_size,
                              hipStream_t stream) {
    const float* x    = (const float*)d_in[0];
    const int*   seq  = (const int*)d_in[1];
    const int*   useq = (const int*)d_in[2];
    // d_in[3] = TextVector: unused (reference overwrites it with weight3[0])
    const float* w1   = (const float*)d_in[4];
    const float* w2   = (const float*)d_in[5];
    const float* w3   = (const float*)d_in[6];
    float* out = (float*)d_out;

    // Scratch layout:
    //   d_out (51.2 MB): [0, 25.6M) xw fp16 table; [25.6M, 38.4M) ea fp16.
    //     Both dead by the time k_gather_n overwrites d_out with f32 output.
    //   d_ws: [0] inter scalar | +256 w1frag 32KB | +32KB w2frag | e1h 12.8MB
    _Float16* xwh   = (_Float16*)d_out;
    _Float16* ea    = (_Float16*)d_out + (size_t)ND * D;
    float*    inter = (float*)d_ws;
    _Float16* w1f   = (_Float16*)((char*)d_ws + 256);
    _Float16* w2f   = (_Float16*)((char*)d_ws + 256 + 32768);
    _Float16* e1h   = (_Float16*)((char*)d_ws + 256 + 65536);

    hipLaunchKernelGGL(k_prep,     dim3(65),             dim3(256), 0, stream, w1, w2, w3, w1f, w2f, inter);
    hipLaunchKernelGGL(k_xw,       dim3((ND + 63) / 64), dim3(256), 0, stream, x, w1f, inter, xwh);
    hipLaunchKernelGGL(k_gather_e, dim3(NE / 4),         dim3(256), 0, stream, seq, xwh, ea);
    hipLaunchKernelGGL(k_gemm_e,   dim3((NE + 63) / 64), dim3(256), 0, stream, ea, w2f, e1h);
    hipLaunchKernelGGL(k_gather_n, dim3(ND / 8),         dim3(256), 0, stream, useq, e1h, out);
}

// Round 5
// 230.286 us; speedup vs baseline: 1.0106x; 1.0106x over previous
//
#include <hip/hip_runtime.h>
#include <hip/hip_fp16.h>

#define ND 100000   // N_NODES
#define NE 50000    // N_EDGES
#define AR 32       // EDGE_ARITY
#define DG 16       // NODE_DEG
#define D  128      // D_IN == D_OUT == TV

typedef _Float16 half8_t __attribute__((ext_vector_type(8)));
typedef _Float16 half4_t __attribute__((ext_vector_type(4)));
typedef float    f32x4_t __attribute__((ext_vector_type(4)));

#define APAD 136   // LDS A-row stride (halves): 16B-aligned, 2-way aliasing free

// ---------------------------------------------------------------------------
// K0: fused prep.  blocks 0..63: w1,w2 -> fragment-major fp16.
//     block 64: inter_nw = mean(cos(w3 rows, w3[0])).
// ---------------------------------------------------------------------------
__global__ __launch_bounds__(256) void k_prep(const float* __restrict__ w1,
                                              const float* __restrict__ w2,
                                              const float* __restrict__ w3,
                                              _Float16* __restrict__ w1f,
                                              _Float16* __restrict__ w2f,
                                              float* __restrict__ inter_out) {
    if (blockIdx.x == 64) {
        __shared__ float red[128];
        int j = threadIdx.x;
        if (j < 128) {
            float dot = 0.f, sq = 0.f, sq0 = 0.f;
            #pragma unroll 8
            for (int k = 0; k < D; ++k) {
                float wj = w3[j * D + k];
                float w0 = w3[k];
                dot += wj * w0;
                sq  += wj * wj;
                sq0 += w0 * w0;
            }
            red[j] = dot / (sqrtf(sq0) * sqrtf(sq));
        }
        __syncthreads();
        if (j == 0) {
            float s = 0.f;
            for (int i = 0; i < 128; ++i) s += red[i];
            inter_out[0] = s / 128.f;
        }
        return;
    }
    int o = blockIdx.x * 256 + threadIdx.x;   // 0..16383
    int j    = o & 7;
    int lane = (o >> 3) & 63;
    int frag = o >> 9;                        // 0..31
    int ntile = frag >> 2, ktile = frag & 3;
    int n = ntile * 16 + (lane & 15);
    int k = ktile * 32 + (lane >> 4) * 8 + j;
    w1f[o] = (_Float16)w1[k * D + n];
    w2f[o] = (_Float16)w2[k * D + n];
}

// ---------------------------------------------------------------------------
// K1: xw = (x @ w1) * inter_nw via MFMA fp16 -> row-major fp16 table.
// ---------------------------------------------------------------------------
__global__ __launch_bounds__(256) void k_xw(const float* __restrict__ x,
                                            const _Float16* __restrict__ w1f_g,
                                            const float* __restrict__ inter_p,
                                            _Float16* __restrict__ xwh) {
    __shared__ _Float16 wfrag[D * D];     // 32 KB, fragment-major
    __shared__ _Float16 xs[64 * APAD];    // 17 KB
    int t = threadIdx.x;
    {
        const float4* src = (const float4*)w1f_g;
        float4* dst = (float4*)wfrag;
        #pragma unroll
        for (int i = 0; i < 8; ++i) dst[i * 256 + t] = src[i * 256 + t];
    }
    int rowbase = blockIdx.x * 64;
    #pragma unroll
    for (int p = 0; p < 8; ++p) {
        int idx = p * 1024 + t * 4;
        int r = idx >> 7, c = idx & 127;
        int grow = rowbase + r;
        float4 v = make_float4(0.f, 0.f, 0.f, 0.f);
        if (grow < ND) v = ((const float4*)x)[(size_t)grow * 32 + (c >> 2)];
        half4_t h = { (_Float16)v.x, (_Float16)v.y, (_Float16)v.z, (_Float16)v.w };
        *(half4_t*)&xs[r * APAD + c] = h;
    }
    __syncthreads();

    int wave = t >> 6, lane = t & 63;
    int quad = lane >> 4, l15 = lane & 15;
    int m0 = wave * 16;
    float inter = inter_p[0];

    half8_t a[4];
    #pragma unroll
    for (int kt = 0; kt < 4; ++kt)
        a[kt] = *(const half8_t*)&xs[(m0 + l15) * APAD + kt * 32 + quad * 8];

    #pragma unroll
    for (int nt = 0; nt < 8; ++nt) {
        f32x4_t acc = {0.f, 0.f, 0.f, 0.f};
        #pragma unroll
        for (int kt = 0; kt < 4; ++kt) {
            half8_t b = *(const half8_t*)&wfrag[((nt * 4 + kt) * 64 + lane) * 8];
            acc = __builtin_amdgcn_mfma_f32_16x16x32_f16(a[kt], b, acc, 0, 0, 0);
        }
        int col = nt * 16 + l15;
        #pragma unroll
        for (int i = 0; i < 4; ++i) {
            int grow = rowbase + m0 + quad * 4 + i;
            if (grow < ND)
                xwh[(size_t)grow * D + col] = (_Float16)(acc[i] * inter);
        }
    }
}

// ---------------------------------------------------------------------------
// K2a: edge gather in ROW-SORTED slot order for L2 locality.
// 4 waves x 4 edges/wave = 16 edges/block, 16 lanes per edge (full 256 B row).
// Counting-sort each edge's 32 slots by key = srow/6250 (16 buckets; invalid
// slots -> key 16, sorted to tail). Valid slots land at ranks [0,cnt) so the
// weight is simply (t<cnt ? 1/cnt : 0). Concurrent waves then sweep the table
// roughly in row order -> sliding L2-resident window.
// ---------------------------------------------------------------------------
__global__ __launch_bounds__(256) void k_gather_e(const int* __restrict__ seq,
                                                  const _Float16* __restrict__ xwh,
                                                  _Float16* __restrict__ ea) {
    __shared__ int srt[16 * AR];   // 2 KB: per-edge sorted slot rows
    int t = threadIdx.x;
    int wave = t >> 6, lane = t & 63;
    int e = lane >> 4, l16 = lane & 15;
    int le = wave * 4 + e;                   // edge-in-block 0..15
    int eg = blockIdx.x * 16 + le;           // global edge (3125*16 == 50000)

    int2 sv = ((const int2*)seq)[(size_t)eg * 16 + l16];  // slots 2*l16, 2*l16+1
    int sh = e * 16;
    unsigned long long b0 = __ballot(sv.x > 0);
    unsigned long long b1 = __ballot(sv.y > 0);
    unsigned int f0 = (unsigned int)(b0 >> sh) & 0xFFFFu;
    unsigned int f1 = (unsigned int)(b1 >> sh) & 0xFFFFu;
    int cnt = __popc(f0) + __popc(f1);
    bool allv = (cnt == 0);                  // degenerate: all slots 0
    if (allv) cnt = AR;
    float wvf = 1.f / (float)cnt;
    bool v0 = (sv.x > 0) | allv, v1 = (sv.y > 0) | allv;
    int key0 = v0 ? (sv.x / 6250) : 16;
    int key1 = v1 ? (sv.y / 6250) : 16;

    unsigned int lowj  = (1u << l16) - 1u;
    unsigned int lowj1 = lowj | (1u << l16);
    int off = 0, r0 = 0, r1 = 0;
    #pragma unroll
    for (int cv = 0; cv <= 16; ++cv) {
        unsigned long long m0 = __ballot(key0 == cv);
        unsigned long long m1 = __ballot(key1 == cv);
        unsigned int g0 = (unsigned int)(m0 >> sh) & 0xFFFFu;
        unsigned int g1 = (unsigned int)(m1 >> sh) & 0xFFFFu;
        if (key0 == cv) r0 = off + __popc(g0 & lowj)  + __popc(g1 & lowj);
        if (key1 == cv) r1 = off + __popc(g0 & lowj1) + __popc(g1 & lowj);
        off += __popc(g0) + __popc(g1);
    }
    srt[le * AR + r0] = sv.x;
    srt[le * AR + r1] = sv.y;
    // producer == consumer wave for srt[le]: lgkmcnt ordering suffices, no barrier.

    float acc[8] = {0.f, 0.f, 0.f, 0.f, 0.f, 0.f, 0.f, 0.f};
    int colOff = l16 * 8;
    #pragma unroll
    for (int tg = 0; tg < 8; ++tg) {
        int4 sr = *(const int4*)&srt[le * AR + tg * 4];   // broadcast read
        int rows[4] = { sr.x, sr.y, sr.z, sr.w };
        #pragma unroll
        for (int u = 0; u < 4; ++u) {
            int tt = tg * 4 + u;
            float w = (tt < cnt) ? wvf : 0.f;
            half8_t v = *(const half8_t*)(xwh + (size_t)rows[u] * D + colOff);
            #pragma unroll
            for (int jj = 0; jj < 8; ++jj)
                acc[jj] = fmaf(w, (float)v[jj], acc[jj]);
        }
    }
    half8_t h;
    #pragma unroll
    for (int jj = 0; jj < 8; ++jj) h[jj] = (_Float16)fmaxf(acc[jj], 0.f);
    f32x4_t hv = *(f32x4_t*)&h;
    __builtin_nontemporal_store(hv, (f32x4_t*)(ea + (size_t)eg * D + colOff));
}

// ---------------------------------------------------------------------------
// K2b: e1 = ea @ w2 via MFMA (row-major fp16 in/out).
// ---------------------------------------------------------------------------
__global__ __launch_bounds__(256) void k_gemm_e(const _Float16* __restrict__ ea,
                                                const _Float16* __restrict__ w2f_g,
                                                _Float16* __restrict__ e1h) {
    __shared__ _Float16 wfrag[D * D];
    __shared__ _Float16 et[64 * APAD];
    int t = threadIdx.x;
    {
        const float4* src = (const float4*)w2f_g;
        float4* dst = (float4*)wfrag;
        #pragma unroll
        for (int i = 0; i < 8; ++i) dst[i * 256 + t] = src[i * 256 + t];
    }
    int rowbase = blockIdx.x * 64;
    #pragma unroll
    for (int p = 0; p < 4; ++p) {
        int hidx = p * 2048 + t * 8;
        int r = hidx >> 7, c = hidx & 127;
        int grow = rowbase + r;
        int gs = (grow < NE) ? grow : (NE - 1);
        half8_t v = *(const half8_t*)(ea + (size_t)gs * D + c);
        *(half8_t*)&et[r * APAD + c] = v;
    }
    __syncthreads();

    int wave = t >> 6, lane = t & 63;
    int quad = lane >> 4, l15 = lane & 15;
    int m0 = wave * 16;

    half8_t a[4];
    #pragma unroll
    for (int kt = 0; kt < 4; ++kt)
        a[kt] = *(const half8_t*)&et[(m0 + l15) * APAD + kt * 32 + quad * 8];

    #pragma unroll
    for (int nt = 0; nt < 8; ++nt) {
        f32x4_t acc = {0.f, 0.f, 0.f, 0.f};
        #pragma unroll
        for (int kt = 0; kt < 4; ++kt) {
            half8_t b = *(const half8_t*)&wfrag[((nt * 4 + kt) * 64 + lane) * 8];
            acc = __builtin_amdgcn_mfma_f32_16x16x32_f16(a[kt], b, acc, 0, 0, 0);
        }
        int col = nt * 16 + l15;
        #pragma unroll
        for (int i = 0; i < 4; ++i) {
            int grow = rowbase + m0 + quad * 4 + i;
            if (grow < NE)
                e1h[(size_t)grow * D + col] = (_Float16)acc[i];
        }
    }
}

// ---------------------------------------------------------------------------
// K3: node gather in ROW-SORTED slot order. 16 nodes/block, 16 lanes/node,
// 1 slot per lane. Same counting-sort trick (buckets of 3125 edge-rows).
// ---------------------------------------------------------------------------
__global__ __launch_bounds__(256) void k_gather_n(const int* __restrict__ useq,
                                                  const _Float16* __restrict__ e1h,
                                                  float* __restrict__ out) {
    __shared__ int srt[16 * DG];   // 1 KB
    int t = threadIdx.x;
    int wave = t >> 6, lane = t & 63;
    int nd = lane >> 4, l16 = lane & 15;
    int ln = wave * 4 + nd;                  // node-in-block 0..15
    int ng = blockIdx.x * 16 + ln;           // global node (6250*16 == 100000)

    int sval = useq[(size_t)ng * DG + l16];
    int sh = nd * 16;
    unsigned long long b = __ballot(sval > 0);
    unsigned int f = (unsigned int)(b >> sh) & 0xFFFFu;
    int cnt = __popc(f);
    bool allv = (cnt == 0);
    if (allv) cnt = DG;
    float wvf = 1.f / (float)cnt;
    bool v = (sval > 0) | allv;
    int key = v ? (sval / 3125) : 16;

    unsigned int lowj = (1u << l16) - 1u;
    int off = 0, r = 0;
    #pragma unroll
    for (int cv = 0; cv <= 16; ++cv) {
        unsigned long long m = __ballot(key == cv);
        unsigned int g = (unsigned int)(m >> sh) & 0xFFFFu;
        if (key == cv) r = off + __popc(g & lowj);
        off += __popc(g);
    }
    srt[ln * DG + r] = sval;

    float acc[8] = {0.f, 0.f, 0.f, 0.f, 0.f, 0.f, 0.f, 0.f};
    int colOff = l16 * 8;
    #pragma unroll
    for (int tg = 0; tg < 4; ++tg) {
        int4 sr = *(const int4*)&srt[ln * DG + tg * 4];
        int rows[4] = { sr.x, sr.y, sr.z, sr.w };
        #pragma unroll
        for (int u = 0; u < 4; ++u) {
            int tt = tg * 4 + u;
            float w = (tt < cnt) ? wvf : 0.f;
            half8_t vv = *(const half8_t*)(e1h + (size_t)rows[u] * D + colOff);
            #pragma unroll
            for (int jj = 0; jj < 8; ++jj)
                acc[jj] = fmaf(w, (float)vv[jj], acc[jj]);
        }
    }
    f32x4_t o0 = { acc[0], acc[1], acc[2], acc[3] };
    f32x4_t o1 = { acc[4], acc[5], acc[6], acc[7] };
    f32x4_t* p = (f32x4_t*)(out + (size_t)ng * D + colOff);
    __builtin_nontemporal_store(o0, p);
    __builtin_nontemporal_store(o1, p + 1);
}

// ---------------------------------------------------------------------------
extern "C" void kernel_launch(void* const* d_in, const int* in_sizes, int n_in,
                              void* d_out, int out_size, void* d_ws, size_t ws_size,
                              hipStream_t stream) {
    const float* x    = (const float*)d_in[0];
    const int*   seq  = (const int*)d_in[1];
    const int*   useq = (const int*)d_in[2];
    // d_in[3] = TextVector: unused (reference overwrites it with weight3[0])
    const float* w1   = (const float*)d_in[4];
    const float* w2   = (const float*)d_in[5];
    const float* w3   = (const float*)d_in[6];
    float* out = (float*)d_out;

    // Scratch: d_out hosts xwh [0,25.6M) and ea [25.6M,38.4M) (both dead
    // before k_gather_n overwrites d_out with the f32 output).
    // d_ws: inter scalar | w1frag 32KB | w2frag 32KB | e1h 12.8MB.
    _Float16* xwh   = (_Float16*)d_out;
    _Float16* ea    = (_Float16*)d_out + (size_t)ND * D;
    float*    inter = (float*)d_ws;
    _Float16* w1f   = (_Float16*)((char*)d_ws + 256);
    _Float16* w2f   = (_Float16*)((char*)d_ws + 256 + 32768);
    _Float16* e1h   = (_Float16*)((char*)d_ws + 256 + 65536);

    hipLaunchKernelGGL(k_prep,     dim3(65),             dim3(256), 0, stream, w1, w2, w3, w1f, w2f, inter);
    hipLaunchKernelGGL(k_xw,       dim3((ND + 63) / 64), dim3(256), 0, stream, x, w1f, inter, xwh);
    hipLaunchKernelGGL(k_gather_e, dim3(NE / 16),        dim3(256), 0, stream, seq, xwh, ea);
    hipLaunchKernelGGL(k_gemm_e,   dim3((NE + 63) / 64), dim3(256), 0, stream, ea, w2f, e1h);
    hipLaunchKernelGGL(k_gather_n, dim3(ND / 16),        dim3(256), 0, stream, useq, e1h, out);
}